// Round 7
// baseline (388.702 us; speedup 1.0000x reference)
//
#include <hip/hip_runtime.h>
#include <hip/hip_bf16.h>
#include <cstdint>
#include <cstddef>

// Problem constants (fixed by the reference):
#define TTOK 4096
#define DM   1024
#define NE   8
#define KTOP 2
#define FFD  1024
#define CPER 1024       // TTOK*KTOP/NE tokens per expert (balanced)
#define MROWS 12288     // 8192 MoE permuted rows + 4096 shared rows
#define G2BLK 384       // gemm2 grid size; <= 512 co-resident at (256,2)

// Journal:
//  - R10: hand-counted vmcnt(N) dbuf in gemm1 REGRESSED 62->74 (compiler
//    drains vmcnt(0) before ds_reads of global_load_lds'd LDS; m131).
//  - R11: __launch_bounds__(256,4) spilled the 128-AGPR acc. (256,2) is a
//    HARD floor for the GEMMs.
//  - R12: gemm2 128x256 retile neutral. gemm1 is ~62 of ~296 us.
//  - R13: atomic-combine fusion +44 us (cross-XCD f32 atomics on data path).
//    REVERTED. prep+transw merge kept. Merged kernel: 75 us (BEST transw).
//  - R14: transw stripe-pipeline 75->83 (prefetch drained by barrier).
//  - R15: barrier-free wave-private transpose 83->91. Across R13/14/15,
//    hbm_gbps ~ OccupancyPercent (1.74/1.58/1.47 TB/s at 45/38/29%):
//    transw is latency-bound streaming; TLP is the ONLY lever. R13's
//    simple 6912-block version wins. RESTORED this round.
//  - R16 (this round): combine launch deleted - fused into gemm2 behind an
//    all-resident barrier (384 blocks <= 512 capacity at (256,2); counter
//    barrier, spin in thread 0 only). Removes one launch + drain boundary.
//    Accounting says ~70-90 us of wall time is inter-launch overhead.

typedef __attribute__((ext_vector_type(8))) short frag8;   // 8 bf16 = 4 VGPRs
typedef __attribute__((ext_vector_type(4))) float f32x4;   // MFMA accumulator

static __device__ __forceinline__ unsigned short f2bf(float f) {
  unsigned int u = __float_as_uint(f);
  u += 0x7fff + ((u >> 16) & 1);     // round-to-nearest-even
  return (unsigned short)(u >> 16);
}
static __device__ __forceinline__ float bf2f(unsigned short u) {
  return __uint_as_float((unsigned int)u << 16);
}

static __device__ __forceinline__ void gld_lds16(const unsigned short* g, unsigned short* l) {
  __builtin_amdgcn_global_load_lds(
      (const __attribute__((address_space(1))) unsigned int*)g,
      (__attribute__((address_space(3))) unsigned int*)l,
      16, 0, 0);
}

// BK=64 tile: rows x 8 segments of 16B. global_load_lds writes LINEAR LDS
// (wave base + lane*16B; per-lane LDS ptr ignored - m104/m108) -> bank swizzle
// on the GLOBAL side: lane filling linear slot seg fetches global segment
// cs=(seg&7)^(r&7); XOR involutive -> reader finds global (r,c) at
// lds_slot64(r,c). R4 measured SQ_LDS_BANK_CONFLICT == 0 with this pattern.
static __device__ __forceinline__ int lds_slot64(int r, int c) {
  return r * 8 + (c ^ (r & 7));
}

static __device__ __forceinline__ void stage_tile64(const unsigned short* __restrict__ src,
                                                    int row0, int k0,
                                                    unsigned short* lds, int tid) {
#pragma unroll
  for (int it = 0; it < 4; ++it) {
    int seg = it * 256 + tid;              // 1024 linear 16B slots
    int r = seg >> 3;                      // tile row
    int cs = (seg & 7) ^ (r & 7);          // swizzled global column segment
    gld_lds16(src + (size_t)(row0 + r) * 1024 + k0 + cs * 8, lds + seg * 8);
  }
}

// XCD-locality block swizzle for grid(8,96): XCD = linear_id % 8; each XCD
// owns 12 consecutive y-tiles (all x). R5 measured FETCH 117->54.6 MB.
static __device__ __forceinline__ void swizzle_xy(int& x, int& y) {
  int L = blockIdx.y * 8 + blockIdx.x;
  int xcd = L & 7;
  int s = L >> 3;                    // 0..95
  y = xcd * 12 + s % 12;
  x = s / 12;
}

// gemm2 grid is (4,96) = 384 blocks. Same stripe ownership as gemm1's swizzle
// (XCD k owns y in [12k, 12k+11]) so gemm2's A (= H) reads hit the L2 of the
// XCD that produced that stripe in gemm1.
static __device__ __forceinline__ void swizzle_xy4(int& x, int& y) {
  int L = blockIdx.y * 4 + blockIdx.x;   // 0..383
  int xcd = L & 7;
  int s = L >> 3;                        // 0..47
  y = xcd * 12 + s % 12;
  x = s / 12;                            // 0..3
}

// ---------------- merged prep + transpose/cast (R13 verified, 75 us) --------
// grid (16,16,28): z<27 = transpose+cast one of the 27 1024x1024 weight mats
// (64x64 tiles, float4 reads, LDS stride 65); z==27 = prep (routing + hidden
// f32->bf16 + shared sigmoid gate), 256 blocks x 16 rows. Max-TLP structure:
// 7168 blocks total (R15 lesson: transw throughput ~ occupancy).
__global__ void prep_transw_kernel(
    const float* __restrict__ wg, const float* __restrict__ wu,
    const float* __restrict__ wd, const float* __restrict__ sg,
    const float* __restrict__ su, const float* __restrict__ sd,
    unsigned short* __restrict__ owg, unsigned short* __restrict__ owu,
    unsigned short* __restrict__ owd,
    const float* __restrict__ x, const float* __restrict__ gw,
    const int* __restrict__ idx, const float* __restrict__ tw,
    int* __restrict__ cnt, int* __restrict__ rowsrc, int* __restrict__ inv,
    float* __restrict__ rowscale, unsigned short* __restrict__ xb) {
  int z = blockIdx.z;
  if (z == 27) {
    // ---- prep branch: 256 blocks ----
    int bid = blockIdx.y * 16 + blockIdx.x;        // 0..255
    if (bid < 32) {
      int i = bid * 256 + threadIdx.x;             // i < TTOK*KTOP
      int e = idx[i];
      int pos = atomicAdd(&cnt[e], 1);             // order within expert irrelevant
      int j = e * CPER + pos;
      rowsrc[j] = i >> 1;                          // token id (KTOP==2)
      rowscale[j] = tw[i];                         // topk weight -> gemm2 epilogue
      inv[i] = j;                                  // inverse perm for combine
      if (i < TTOK) rowsrc[8192 + i] = i;          // shared rows: identity
    }
    int wave = threadIdx.x >> 6;
    int lane = threadIdx.x & 63;
    const float4* wr = (const float4*)gw;
#pragma unroll
    for (int s = 0; s < 4; ++s) {
      int row = bid * 16 + wave * 4 + s;           // 16 rows/block
      const float4* xr = (const float4*)(x + (size_t)row * 1024);
      ushort4* ob = (ushort4*)(xb + (size_t)row * 1024);
      float acc = 0.f;
#pragma unroll
      for (int c = 0; c < 4; ++c) {
        int k = lane + 64 * c;
        float4 v = xr[k];
        float4 g = wr[k];
        acc += v.x * g.x + v.y * g.y + v.z * g.z + v.w * g.w;
        ushort4 o;
        o.x = f2bf(v.x); o.y = f2bf(v.y); o.z = f2bf(v.z); o.w = f2bf(v.w);
        ob[k] = o;
      }
#pragma unroll
      for (int off = 32; off; off >>= 1) acc += __shfl_down(acc, off);
      if (lane == 0) rowscale[8192 + row] = 1.f / (1.f + __expf(-acc));
    }
    return;
  }
  // ---- transw branch (R13/R0-verified body) ----
  const float* src; unsigned short* dst;
  if (z < 8)       { src = wg + (size_t)z * 1048576;        dst = owg + (size_t)z * 1048576; }
  else if (z < 16) { src = wu + (size_t)(z - 8) * 1048576;  dst = owu + (size_t)(z - 8) * 1048576; }
  else if (z < 24) { src = wd + (size_t)(z - 16) * 1048576; dst = owd + (size_t)(z - 16) * 1048576; }
  else if (z == 24){ src = sg; dst = owg + (size_t)8 * 1048576; }
  else if (z == 25){ src = su; dst = owu + (size_t)8 * 1048576; }
  else             { src = sd; dst = owd + (size_t)8 * 1048576; }
  __shared__ float tile[64][65];
  int bx = blockIdx.x * 64;   // src col base
  int by = blockIdx.y * 64;   // src row base
  int c4 = threadIdx.x & 15;  // float4 chunk within row
  int r0 = threadIdx.x >> 4;  // 0..15
#pragma unroll
  for (int i = 0; i < 4; ++i) {
    int r = r0 + 16 * i;
    float4 v = *(const float4*)&src[(size_t)(by + r) * 1024 + bx + c4 * 4];
    tile[r][c4 * 4 + 0] = v.x; tile[r][c4 * 4 + 1] = v.y;
    tile[r][c4 * 4 + 2] = v.z; tile[r][c4 * 4 + 3] = v.w;
  }
  __syncthreads();
#pragma unroll
  for (int i = 0; i < 4; ++i) {
    int f = r0 + 16 * i;       // dst row = src col bx+f
    ushort4 o;
    o.x = f2bf(tile[c4 * 4 + 0][f]);
    o.y = f2bf(tile[c4 * 4 + 1][f]);
    o.z = f2bf(tile[c4 * 4 + 2][f]);
    o.w = f2bf(tile[c4 * 4 + 3][f]);
    *(ushort4*)&dst[(size_t)(bx + f) * 1024 + by + c4 * 4] = o;
  }
}

// Expert id for a 128-row M-block: y<64 -> MoE expert y/8; else shared (8).
static __device__ __forceinline__ int eid_of(int y) { return (y < 64) ? (y >> 3) : 8; }

// ---------------- GEMM1: H = silu(A @ Wg) * (A @ Wu), bf16 out ----------------
// Byte-for-byte the R0-verified 62 us version. A gathered on the fly from the
// 8.4 MB bf16 Xbf via rowsrc (R9: free). BK=64 halves barrier-drain count;
// LDS 48KB/block -> 2 blocks/CU (register-capped: 108 VGPR + 128 AGPR).
__global__ __launch_bounds__(256, 2) void gemm1_kernel(
    const unsigned short* __restrict__ A, const int* __restrict__ rowsrc,
    const unsigned short* __restrict__ Bg, const unsigned short* __restrict__ Bu,
    unsigned short* __restrict__ H) {
  __shared__ __align__(16) unsigned short As[128 * 64];
  __shared__ __align__(16) unsigned short Bgs[128 * 64];
  __shared__ __align__(16) unsigned short Bus[128 * 64];
  int tid = threadIdx.x;
  int bx, by;
  swizzle_xy(bx, by);
  int e = eid_of(by);
  int row0 = by * 128;
  int col0 = bx * 128;
  const unsigned short* Bge = Bg + (size_t)e * 1048576;
  const unsigned short* Bue = Bu + (size_t)e * 1048576;

  // per-thread A staging sources (fixed across K): 4 segs, global-side swizzle
  const unsigned short* pA[4];
#pragma unroll
  for (int it = 0; it < 4; ++it) {
    int seg = it * 256 + tid;
    int r = seg >> 3;
    int cs = (seg & 7) ^ (r & 7);
    pA[it] = A + (size_t)rowsrc[row0 + r] * 1024 + cs * 8;
  }

  int wave = tid >> 6, lane = tid & 63;
  int wm = wave >> 1, wn = wave & 1;             // 2x2 wave grid, 64x64 per wave
  int lr = lane & 15, q = lane >> 4;

  f32x4 accg[4][4], accu[4][4];
#pragma unroll
  for (int i = 0; i < 4; ++i)
#pragma unroll
    for (int j = 0; j < 4; ++j) {
      accg[i][j] = (f32x4){0.f, 0.f, 0.f, 0.f};
      accu[i][j] = (f32x4){0.f, 0.f, 0.f, 0.f};
    }

  for (int kt = 0; kt < 1024; kt += 64) {
#pragma unroll
    for (int it = 0; it < 4; ++it)
      gld_lds16(pA[it] + kt, As + (it * 256 + tid) * 8);
    stage_tile64(Bge, col0, kt, Bgs, tid);
    stage_tile64(Bue, col0, kt, Bus, tid);
    __syncthreads();                             // drains vmcnt for global_load_lds
#pragma unroll
    for (int kk = 0; kk < 2; ++kk) {
      int c = kk * 4 + q;
      frag8 a[4], b0[4], b1[4];
#pragma unroll
      for (int i = 0; i < 4; ++i) {
        int r = wm * 64 + i * 16 + lr;
        a[i] = *(const frag8*)&As[lds_slot64(r, c) * 8];
      }
#pragma unroll
      for (int j = 0; j < 4; ++j) {
        int r = wn * 64 + j * 16 + lr;
        b0[j] = *(const frag8*)&Bgs[lds_slot64(r, c) * 8];
        b1[j] = *(const frag8*)&Bus[lds_slot64(r, c) * 8];
      }
#pragma unroll
      for (int i = 0; i < 4; ++i)
#pragma unroll
        for (int j = 0; j < 4; ++j) {
          accg[i][j] = __builtin_amdgcn_mfma_f32_16x16x32_bf16(a[i], b0[j], accg[i][j], 0, 0, 0);
          accu[i][j] = __builtin_amdgcn_mfma_f32_16x16x32_bf16(a[i], b1[j], accu[i][j], 0, 0, 0);
        }
    }
    __syncthreads();
  }
#pragma unroll
  for (int i = 0; i < 4; ++i)
#pragma unroll
    for (int j = 0; j < 4; ++j)
#pragma unroll
      for (int r = 0; r < 4; ++r) {
        int m = row0 + wm * 64 + i * 16 + q * 4 + r;   // C/D: row=quad*4+reg
        int n = col0 + wn * 64 + j * 16 + lr;          //       col=lane&15
        float gv = accg[i][j][r];
        float hv = gv / (1.f + __expf(-gv)) * accu[i][j][r];
        H[(size_t)m * 1024 + n] = f2bf(hv);
      }
}

// ---------------- GEMM2 (+fused combine): Y then out ----------------
// K-loop + Y epilogue byte-identical to R12-verified gemm2 (128x256 tile,
// BK=64, acc[4][8], (256,2)). R16: after the Y store, an all-resident
// counter barrier (384 blocks <= 512 capacity at (256,2); spin only in
// thread 0 of each block -> no deadlock), then the same blocks grid-stride
// the verified combine loop. Deletes the combine launch + drain boundary.
__global__ __launch_bounds__(256, 2) void gemm2_kernel(
    const unsigned short* __restrict__ A, const unsigned short* __restrict__ B,
    const float* __restrict__ rowscale, unsigned short* __restrict__ Y,
    const int* __restrict__ inv, float* __restrict__ out,
    int* __restrict__ bar) {
  __shared__ __align__(16) unsigned short As[128 * 64];
  __shared__ __align__(16) unsigned short Bs[256 * 64];
  int tid = threadIdx.x;
  int bx, by;
  swizzle_xy4(bx, by);
  int e = eid_of(by);
  int row0 = by * 128;
  int col0 = bx * 256;
  const unsigned short* Be = B + (size_t)e * 1048576;

  int wave = tid >> 6, lane = tid & 63;
  int wm = wave >> 1, wn = wave & 1;             // M halves of 64, N halves of 128
  int lr = lane & 15, q = lane >> 4;

  f32x4 acc[4][8];
#pragma unroll
  for (int i = 0; i < 4; ++i)
#pragma unroll
    for (int j = 0; j < 8; ++j) acc[i][j] = (f32x4){0.f, 0.f, 0.f, 0.f};

  for (int kt = 0; kt < 1024; kt += 64) {
    stage_tile64(A, row0, kt, As, tid);
    // B tile: 256 rows x 64 cols, 8 segs/thread, same 8-seg global-side swizzle
#pragma unroll
    for (int it = 0; it < 8; ++it) {
      int seg = it * 256 + tid;              // 2048 linear 16B slots
      int r = seg >> 3;                      // 0..255
      int cs = (seg & 7) ^ (r & 7);
      gld_lds16(Be + (size_t)(col0 + r) * 1024 + kt + cs * 8, Bs + seg * 8);
    }
    __syncthreads();
#pragma unroll
    for (int kk = 0; kk < 2; ++kk) {
      int c = kk * 4 + q;
      frag8 a[4], b[8];
#pragma unroll
      for (int i = 0; i < 4; ++i) {
        int r = wm * 64 + i * 16 + lr;
        a[i] = *(const frag8*)&As[lds_slot64(r, c) * 8];
      }
#pragma unroll
      for (int j = 0; j < 8; ++j) {
        int r = wn * 128 + j * 16 + lr;
        b[j] = *(const frag8*)&Bs[lds_slot64(r, c) * 8];
      }
#pragma unroll
      for (int i = 0; i < 4; ++i)
#pragma unroll
        for (int j = 0; j < 8; ++j)
          acc[i][j] = __builtin_amdgcn_mfma_f32_16x16x32_bf16(a[i], b[j], acc[i][j], 0, 0, 0);
    }
    __syncthreads();
  }
#pragma unroll
  for (int i = 0; i < 4; ++i)
#pragma unroll
    for (int r = 0; r < 4; ++r) {
      int m = row0 + wm * 64 + i * 16 + q * 4 + r;
      float sc = rowscale[m];
#pragma unroll
      for (int j = 0; j < 8; ++j) {
        int n = col0 + wn * 128 + j * 16 + lr;
        Y[(size_t)m * 1024 + n] = f2bf(sc * acc[i][j][r]);
      }
    }

  // ---- all-resident barrier: every block's Y visible before combine ----
  __threadfence();                               // release Y stores (device scope)
  __syncthreads();
  if (tid == 0) {
    atomicAdd(bar, 1);
    while (atomicAdd(bar, 0) < G2BLK) {}         // all 384 blocks co-resident
  }
  __syncthreads();
  __threadfence();                               // acquire other blocks' Y

  // ---- fused combine: out[t] = Y[j0] + Y[j1] + Y[8192+t] ----
  int gid = (blockIdx.y * 4 + blockIdx.x) * 256 + tid;   // 0..98303
  for (int slot = gid; slot < TTOK * 256; slot += G2BLK * 256) {
    int t = slot >> 8;
    int c = slot & 255;
    int j0 = inv[2 * t], j1 = inv[2 * t + 1];
    ushort4 a = ((const ushort4*)(Y + (size_t)j0 * 1024))[c];
    ushort4 b = ((const ushort4*)(Y + (size_t)j1 * 1024))[c];
    ushort4 s = ((const ushort4*)(Y + (size_t)(8192 + t) * 1024))[c];
    float4 o;
    o.x = bf2f(a.x) + bf2f(b.x) + bf2f(s.x);
    o.y = bf2f(a.y) + bf2f(b.y) + bf2f(s.y);
    o.z = bf2f(a.z) + bf2f(b.z) + bf2f(s.z);
    o.w = bf2f(a.w) + bf2f(b.w) + bf2f(s.w);
    ((float4*)(out + (size_t)t * 1024))[c] = o;
  }
}

extern "C" void kernel_launch(void* const* d_in, const int* in_sizes, int n_in,
                              void* d_out, int out_size, void* d_ws, size_t ws_size,
                              hipStream_t stream) {
  (void)in_sizes; (void)n_in; (void)out_size; (void)ws_size;
  const float* hidden  = (const float*)d_in[0];
  const float* topk_w  = (const float*)d_in[1];
  const float* w_gate  = (const float*)d_in[2];
  const float* w_up    = (const float*)d_in[3];
  const float* w_down  = (const float*)d_in[4];
  const float* sw_gate = (const float*)d_in[5];
  const float* sw_up   = (const float*)d_in[6];
  const float* sw_down = (const float*)d_in[7];
  const float* sgw     = (const float*)d_in[8];
  const int*   topk_i  = (const int*)d_in[9];
  float* out = (float*)d_out;

  char* p = (char*)d_ws;
  auto alloc = [&](size_t bytes) {
    char* r = p;
    p += (bytes + 255) & ~(size_t)255;
    return r;
  };
  unsigned short* Wg_all = (unsigned short*)alloc((size_t)9 * 1048576 * 2);  // [9][1024][1024]
  unsigned short* Wu_all = (unsigned short*)alloc((size_t)9 * 1048576 * 2);
  unsigned short* Wd_all = (unsigned short*)alloc((size_t)9 * 1048576 * 2);
  unsigned short* Xbf    = (unsigned short*)alloc((size_t)TTOK * 1024 * 2);  // bf16 hidden
  unsigned short* Hall   = (unsigned short*)alloc((size_t)MROWS * 1024 * 2);
  unsigned short* Yall   = (unsigned short*)alloc((size_t)MROWS * 1024 * 2);
  int*   cnt      = (int*)alloc(16 * 4);        // [0..7]=routing counters, [8]=barrier
  int*   rowsrc   = (int*)alloc((size_t)MROWS * 4);
  int*   inv      = (int*)alloc((size_t)TTOK * KTOP * 4);
  float* rowscale = (float*)alloc((size_t)MROWS * 4);

  hipMemsetAsync(cnt, 0, 16 * 4, stream);       // zero counters + barrier

  prep_transw_kernel<<<dim3(16, 16, 28), 256, 0, stream>>>(
      w_gate, w_up, w_down, sw_gate, sw_up, sw_down, Wg_all, Wu_all, Wd_all,
      hidden, sgw, topk_i, topk_w, cnt, rowsrc, inv, rowscale, Xbf);

  gemm1_kernel<<<dim3(8, 96), 256, 0, stream>>>(Xbf, rowsrc, Wg_all, Wu_all, Hall);
  gemm2_kernel<<<dim3(4, 96), 256, 0, stream>>>(Hall, Wd_all, rowscale, Yall,
                                                inv, out, cnt + 8);
}

// Round 8
// 278.870 us; speedup vs baseline: 1.3938x; 1.3938x over previous
//
#include <hip/hip_runtime.h>
#include <hip/hip_bf16.h>
#include <cstdint>
#include <cstddef>

// Problem constants (fixed by the reference):
#define TTOK 4096
#define DM   1024
#define NE   8
#define KTOP 2
#define FFD  1024
#define CPER 1024       // TTOK*KTOP/NE tokens per expert (balanced)
#define MROWS 12288     // 8192 MoE permuted rows + 4096 shared rows

// Journal:
//  - R10: hand-counted vmcnt(N) dbuf in gemm1 REGRESSED 62->74 (compiler
//    drains vmcnt(0) before ds_reads of global_load_lds'd LDS; m131).
//  - R11: (256,4) spilled the 128-AGPR acc. (256,2) is a HARD floor.
//  - R12: gemm2 128x256 retile neutral vs 128x128.
//  - R13: atomic-combine fusion +44 us (cross-XCD f32 atomics on data path).
//    prep+transw merge kept; R13 transw = 75 us BEST (max-TLP 6912 blocks).
//  - R14: transw stripe-pipeline 75->83 (prefetch drained by barrier). 290.9 best total.
//  - R15: wave-private transpose 83->91. transw is latency-bound streaming;
//    hbm_gbps ~ occupancy. TLP is the only lever.
//  - R16: all-resident spin-barrier fusion of combine into gemm2: gemm2
//    60->150 us (384 waves spinning device-scope atomicAdd on one line
//    serialize at the coherence point). ANY cross-XCD sync/atomic in the
//    hot path costs more than a launch boundary. REVERTED.
//  - R17 (this round): best-known composition, first time together:
//    R13 prep_transw + R0 gemm1 + R12 gemm2 + R0 combine. Plus: memset(cnt)
//    dispatch deleted - routing uses pos = atomicAdd(&cnt[e],1) & (CPER-1);
//    balanced routing adds exactly 1024/expert/replay so the mask is a
//    bijection every run with NO reset (2^32 % 1024 == 0).

typedef __attribute__((ext_vector_type(8))) short frag8;   // 8 bf16 = 4 VGPRs
typedef __attribute__((ext_vector_type(4))) float f32x4;   // MFMA accumulator

static __device__ __forceinline__ unsigned short f2bf(float f) {
  unsigned int u = __float_as_uint(f);
  u += 0x7fff + ((u >> 16) & 1);     // round-to-nearest-even
  return (unsigned short)(u >> 16);
}
static __device__ __forceinline__ float bf2f(unsigned short u) {
  return __uint_as_float((unsigned int)u << 16);
}

static __device__ __forceinline__ void gld_lds16(const unsigned short* g, unsigned short* l) {
  __builtin_amdgcn_global_load_lds(
      (const __attribute__((address_space(1))) unsigned int*)g,
      (__attribute__((address_space(3))) unsigned int*)l,
      16, 0, 0);
}

// BK=64 tile: rows x 8 segments of 16B. global_load_lds writes LINEAR LDS
// (wave base + lane*16B; per-lane LDS ptr ignored - m104/m108) -> bank swizzle
// on the GLOBAL side: lane filling linear slot seg fetches global segment
// cs=(seg&7)^(r&7); XOR involutive -> reader finds global (r,c) at
// lds_slot64(r,c). R4 measured SQ_LDS_BANK_CONFLICT == 0 with this pattern.
static __device__ __forceinline__ int lds_slot64(int r, int c) {
  return r * 8 + (c ^ (r & 7));
}

static __device__ __forceinline__ void stage_tile64(const unsigned short* __restrict__ src,
                                                    int row0, int k0,
                                                    unsigned short* lds, int tid) {
#pragma unroll
  for (int it = 0; it < 4; ++it) {
    int seg = it * 256 + tid;              // 1024 linear 16B slots
    int r = seg >> 3;                      // tile row
    int cs = (seg & 7) ^ (r & 7);          // swizzled global column segment
    gld_lds16(src + (size_t)(row0 + r) * 1024 + k0 + cs * 8, lds + seg * 8);
  }
}

// XCD-locality block swizzle for grid(8,96): XCD = linear_id % 8; each XCD
// owns 12 consecutive y-tiles (all x). R5 measured FETCH 117->54.6 MB.
static __device__ __forceinline__ void swizzle_xy(int& x, int& y) {
  int L = blockIdx.y * 8 + blockIdx.x;
  int xcd = L & 7;
  int s = L >> 3;                    // 0..95
  y = xcd * 12 + s % 12;
  x = s / 12;
}

// gemm2 grid is (4,96) = 384 blocks. Same stripe ownership as gemm1's swizzle
// (XCD k owns y in [12k, 12k+11]) so gemm2's A (= H) reads hit the L2 of the
// XCD that produced that stripe in gemm1.
static __device__ __forceinline__ void swizzle_xy4(int& x, int& y) {
  int L = blockIdx.y * 4 + blockIdx.x;   // 0..383
  int xcd = L & 7;
  int s = L >> 3;                        // 0..47
  y = xcd * 12 + s % 12;
  x = s / 12;                            // 0..3
}

// ---------------- merged prep + transpose/cast (R13 verified, 75 us) --------
// grid (16,16,28): z<27 = transpose+cast one of the 27 1024x1024 weight mats
// (64x64 tiles, float4 reads, LDS stride 65); z==27 = prep (routing + hidden
// f32->bf16 + shared sigmoid gate), 256 blocks x 16 rows. Max-TLP structure:
// 7168 blocks total (R15 lesson: transw throughput ~ occupancy).
__global__ void prep_transw_kernel(
    const float* __restrict__ wg, const float* __restrict__ wu,
    const float* __restrict__ wd, const float* __restrict__ sg,
    const float* __restrict__ su, const float* __restrict__ sd,
    unsigned short* __restrict__ owg, unsigned short* __restrict__ owu,
    unsigned short* __restrict__ owd,
    const float* __restrict__ x, const float* __restrict__ gw,
    const int* __restrict__ idx, const float* __restrict__ tw,
    int* __restrict__ cnt, int* __restrict__ rowsrc, int* __restrict__ inv,
    float* __restrict__ rowscale, unsigned short* __restrict__ xb) {
  int z = blockIdx.z;
  if (z == 27) {
    // ---- prep branch: 256 blocks ----
    int bid = blockIdx.y * 16 + blockIdx.x;        // 0..255
    if (bid < 32) {
      int i = bid * 256 + threadIdx.x;             // i < TTOK*KTOP
      int e = idx[i];
      // No-reset counter: each replay adds exactly CPER per expert (balanced
      // routing), so masking by CPER-1 is a bijection onto 0..1023 every run
      // regardless of the persistent counter value. Deletes the memset launch.
      int pos = atomicAdd(&cnt[e], 1) & (CPER - 1);
      int j = e * CPER + pos;
      rowsrc[j] = i >> 1;                          // token id (KTOP==2)
      rowscale[j] = tw[i];                         // topk weight -> gemm2 epilogue
      inv[i] = j;                                  // inverse perm for combine
      if (i < TTOK) rowsrc[8192 + i] = i;          // shared rows: identity
    }
    int wave = threadIdx.x >> 6;
    int lane = threadIdx.x & 63;
    const float4* wr = (const float4*)gw;
#pragma unroll
    for (int s = 0; s < 4; ++s) {
      int row = bid * 16 + wave * 4 + s;           // 16 rows/block
      const float4* xr = (const float4*)(x + (size_t)row * 1024);
      ushort4* ob = (ushort4*)(xb + (size_t)row * 1024);
      float acc = 0.f;
#pragma unroll
      for (int c = 0; c < 4; ++c) {
        int k = lane + 64 * c;
        float4 v = xr[k];
        float4 g = wr[k];
        acc += v.x * g.x + v.y * g.y + v.z * g.z + v.w * g.w;
        ushort4 o;
        o.x = f2bf(v.x); o.y = f2bf(v.y); o.z = f2bf(v.z); o.w = f2bf(v.w);
        ob[k] = o;
      }
#pragma unroll
      for (int off = 32; off; off >>= 1) acc += __shfl_down(acc, off);
      if (lane == 0) rowscale[8192 + row] = 1.f / (1.f + __expf(-acc));
    }
    return;
  }
  // ---- transw branch (R13/R0-verified body) ----
  const float* src; unsigned short* dst;
  if (z < 8)       { src = wg + (size_t)z * 1048576;        dst = owg + (size_t)z * 1048576; }
  else if (z < 16) { src = wu + (size_t)(z - 8) * 1048576;  dst = owu + (size_t)(z - 8) * 1048576; }
  else if (z < 24) { src = wd + (size_t)(z - 16) * 1048576; dst = owd + (size_t)(z - 16) * 1048576; }
  else if (z == 24){ src = sg; dst = owg + (size_t)8 * 1048576; }
  else if (z == 25){ src = su; dst = owu + (size_t)8 * 1048576; }
  else             { src = sd; dst = owd + (size_t)8 * 1048576; }
  __shared__ float tile[64][65];
  int bx = blockIdx.x * 64;   // src col base
  int by = blockIdx.y * 64;   // src row base
  int c4 = threadIdx.x & 15;  // float4 chunk within row
  int r0 = threadIdx.x >> 4;  // 0..15
#pragma unroll
  for (int i = 0; i < 4; ++i) {
    int r = r0 + 16 * i;
    float4 v = *(const float4*)&src[(size_t)(by + r) * 1024 + bx + c4 * 4];
    tile[r][c4 * 4 + 0] = v.x; tile[r][c4 * 4 + 1] = v.y;
    tile[r][c4 * 4 + 2] = v.z; tile[r][c4 * 4 + 3] = v.w;
  }
  __syncthreads();
#pragma unroll
  for (int i = 0; i < 4; ++i) {
    int f = r0 + 16 * i;       // dst row = src col bx+f
    ushort4 o;
    o.x = f2bf(tile[c4 * 4 + 0][f]);
    o.y = f2bf(tile[c4 * 4 + 1][f]);
    o.z = f2bf(tile[c4 * 4 + 2][f]);
    o.w = f2bf(tile[c4 * 4 + 3][f]);
    *(ushort4*)&dst[(size_t)(bx + f) * 1024 + by + c4 * 4] = o;
  }
}

// Expert id for a 128-row M-block: y<64 -> MoE expert y/8; else shared (8).
static __device__ __forceinline__ int eid_of(int y) { return (y < 64) ? (y >> 3) : 8; }

// ---------------- GEMM1: H = silu(A @ Wg) * (A @ Wu), bf16 out ----------------
// Byte-for-byte the R0-verified 62 us version. A gathered on the fly from the
// 8.4 MB bf16 Xbf via rowsrc (R9: free). BK=64 halves barrier-drain count;
// LDS 48KB/block -> 2 blocks/CU (register-capped: 108 VGPR + 128 AGPR).
__global__ __launch_bounds__(256, 2) void gemm1_kernel(
    const unsigned short* __restrict__ A, const int* __restrict__ rowsrc,
    const unsigned short* __restrict__ Bg, const unsigned short* __restrict__ Bu,
    unsigned short* __restrict__ H) {
  __shared__ __align__(16) unsigned short As[128 * 64];
  __shared__ __align__(16) unsigned short Bgs[128 * 64];
  __shared__ __align__(16) unsigned short Bus[128 * 64];
  int tid = threadIdx.x;
  int bx, by;
  swizzle_xy(bx, by);
  int e = eid_of(by);
  int row0 = by * 128;
  int col0 = bx * 128;
  const unsigned short* Bge = Bg + (size_t)e * 1048576;
  const unsigned short* Bue = Bu + (size_t)e * 1048576;

  // per-thread A staging sources (fixed across K): 4 segs, global-side swizzle
  const unsigned short* pA[4];
#pragma unroll
  for (int it = 0; it < 4; ++it) {
    int seg = it * 256 + tid;
    int r = seg >> 3;
    int cs = (seg & 7) ^ (r & 7);
    pA[it] = A + (size_t)rowsrc[row0 + r] * 1024 + cs * 8;
  }

  int wave = tid >> 6, lane = tid & 63;
  int wm = wave >> 1, wn = wave & 1;             // 2x2 wave grid, 64x64 per wave
  int lr = lane & 15, q = lane >> 4;

  f32x4 accg[4][4], accu[4][4];
#pragma unroll
  for (int i = 0; i < 4; ++i)
#pragma unroll
    for (int j = 0; j < 4; ++j) {
      accg[i][j] = (f32x4){0.f, 0.f, 0.f, 0.f};
      accu[i][j] = (f32x4){0.f, 0.f, 0.f, 0.f};
    }

  for (int kt = 0; kt < 1024; kt += 64) {
#pragma unroll
    for (int it = 0; it < 4; ++it)
      gld_lds16(pA[it] + kt, As + (it * 256 + tid) * 8);
    stage_tile64(Bge, col0, kt, Bgs, tid);
    stage_tile64(Bue, col0, kt, Bus, tid);
    __syncthreads();                             // drains vmcnt for global_load_lds
#pragma unroll
    for (int kk = 0; kk < 2; ++kk) {
      int c = kk * 4 + q;
      frag8 a[4], b0[4], b1[4];
#pragma unroll
      for (int i = 0; i < 4; ++i) {
        int r = wm * 64 + i * 16 + lr;
        a[i] = *(const frag8*)&As[lds_slot64(r, c) * 8];
      }
#pragma unroll
      for (int j = 0; j < 4; ++j) {
        int r = wn * 64 + j * 16 + lr;
        b0[j] = *(const frag8*)&Bgs[lds_slot64(r, c) * 8];
        b1[j] = *(const frag8*)&Bus[lds_slot64(r, c) * 8];
      }
#pragma unroll
      for (int i = 0; i < 4; ++i)
#pragma unroll
        for (int j = 0; j < 4; ++j) {
          accg[i][j] = __builtin_amdgcn_mfma_f32_16x16x32_bf16(a[i], b0[j], accg[i][j], 0, 0, 0);
          accu[i][j] = __builtin_amdgcn_mfma_f32_16x16x32_bf16(a[i], b1[j], accu[i][j], 0, 0, 0);
        }
    }
    __syncthreads();
  }
#pragma unroll
  for (int i = 0; i < 4; ++i)
#pragma unroll
    for (int j = 0; j < 4; ++j)
#pragma unroll
      for (int r = 0; r < 4; ++r) {
        int m = row0 + wm * 64 + i * 16 + q * 4 + r;   // C/D: row=quad*4+reg
        int n = col0 + wn * 64 + j * 16 + lr;          //       col=lane&15
        float gv = accg[i][j][r];
        float hv = gv / (1.f + __expf(-gv)) * accu[i][j][r];
        H[(size_t)m * 1024 + n] = f2bf(hv);
      }
}

// ---------------- GEMM2: Y = rowscale * (A @ Wd), bf16 out ----------------
// R12-verified: 128x256 (MxN), BK=64, 4 waves of 64x128 -> acc[4][8] =
// 128 AGPR, 12 gld_lds/thread/K-step, 64 MFMA/wave/K-step. LDS 48 KB,
// (256,2) register-capped like gemm1. Grid (4,96)=384 blocks.
__global__ __launch_bounds__(256, 2) void gemm2_kernel(
    const unsigned short* __restrict__ A, const unsigned short* __restrict__ B,
    const float* __restrict__ rowscale, unsigned short* __restrict__ Y) {
  __shared__ __align__(16) unsigned short As[128 * 64];
  __shared__ __align__(16) unsigned short Bs[256 * 64];
  int tid = threadIdx.x;
  int bx, by;
  swizzle_xy4(bx, by);
  int e = eid_of(by);
  int row0 = by * 128;
  int col0 = bx * 256;
  const unsigned short* Be = B + (size_t)e * 1048576;

  int wave = tid >> 6, lane = tid & 63;
  int wm = wave >> 1, wn = wave & 1;             // M halves of 64, N halves of 128
  int lr = lane & 15, q = lane >> 4;

  f32x4 acc[4][8];
#pragma unroll
  for (int i = 0; i < 4; ++i)
#pragma unroll
    for (int j = 0; j < 8; ++j) acc[i][j] = (f32x4){0.f, 0.f, 0.f, 0.f};

  for (int kt = 0; kt < 1024; kt += 64) {
    stage_tile64(A, row0, kt, As, tid);
    // B tile: 256 rows x 64 cols, 8 segs/thread, same 8-seg global-side swizzle
#pragma unroll
    for (int it = 0; it < 8; ++it) {
      int seg = it * 256 + tid;              // 2048 linear 16B slots
      int r = seg >> 3;                      // 0..255
      int cs = (seg & 7) ^ (r & 7);
      gld_lds16(Be + (size_t)(col0 + r) * 1024 + kt + cs * 8, Bs + seg * 8);
    }
    __syncthreads();
#pragma unroll
    for (int kk = 0; kk < 2; ++kk) {
      int c = kk * 4 + q;
      frag8 a[4], b[8];
#pragma unroll
      for (int i = 0; i < 4; ++i) {
        int r = wm * 64 + i * 16 + lr;
        a[i] = *(const frag8*)&As[lds_slot64(r, c) * 8];
      }
#pragma unroll
      for (int j = 0; j < 8; ++j) {
        int r = wn * 128 + j * 16 + lr;
        b[j] = *(const frag8*)&Bs[lds_slot64(r, c) * 8];
      }
#pragma unroll
      for (int i = 0; i < 4; ++i)
#pragma unroll
        for (int j = 0; j < 8; ++j)
          acc[i][j] = __builtin_amdgcn_mfma_f32_16x16x32_bf16(a[i], b[j], acc[i][j], 0, 0, 0);
    }
    __syncthreads();
  }
#pragma unroll
  for (int i = 0; i < 4; ++i)
#pragma unroll
    for (int r = 0; r < 4; ++r) {
      int m = row0 + wm * 64 + i * 16 + q * 4 + r;
      float sc = rowscale[m];
#pragma unroll
      for (int j = 0; j < 8; ++j) {
        int n = col0 + wn * 128 + j * 16 + lr;
        Y[(size_t)m * 1024 + n] = f2bf(sc * acc[i][j][r]);
      }
    }
}

// ---------------- final combine: out[t] = Y[j0] + Y[j1] + Y[8192+t] ----------
// Flat slot mapping, 2 independent slots/thread (R8 lesson: avoid one-row
// blocks).
__global__ void combine_kernel(const unsigned short* __restrict__ Y,
                               const int* __restrict__ inv, float* __restrict__ out) {
  int base = blockIdx.x * 256 + threadIdx.x;
#pragma unroll
  for (int k = 0; k < 2; ++k) {
    int slot = base + k * 524288;                // 2048 blocks * 256 threads
    int t = slot >> 8;
    int c = slot & 255;
    int j0 = inv[2 * t], j1 = inv[2 * t + 1];
    ushort4 a = ((const ushort4*)(Y + (size_t)j0 * 1024))[c];
    ushort4 b = ((const ushort4*)(Y + (size_t)j1 * 1024))[c];
    ushort4 s = ((const ushort4*)(Y + (size_t)(8192 + t) * 1024))[c];
    float4 o;
    o.x = bf2f(a.x) + bf2f(b.x) + bf2f(s.x);
    o.y = bf2f(a.y) + bf2f(b.y) + bf2f(s.y);
    o.z = bf2f(a.z) + bf2f(b.z) + bf2f(s.z);
    o.w = bf2f(a.w) + bf2f(b.w) + bf2f(s.w);
    ((float4*)(out + (size_t)t * 1024))[c] = o;
  }
}

extern "C" void kernel_launch(void* const* d_in, const int* in_sizes, int n_in,
                              void* d_out, int out_size, void* d_ws, size_t ws_size,
                              hipStream_t stream) {
  (void)in_sizes; (void)n_in; (void)out_size; (void)ws_size;
  const float* hidden  = (const float*)d_in[0];
  const float* topk_w  = (const float*)d_in[1];
  const float* w_gate  = (const float*)d_in[2];
  const float* w_up    = (const float*)d_in[3];
  const float* w_down  = (const float*)d_in[4];
  const float* sw_gate = (const float*)d_in[5];
  const float* sw_up   = (const float*)d_in[6];
  const float* sw_down = (const float*)d_in[7];
  const float* sgw     = (const float*)d_in[8];
  const int*   topk_i  = (const int*)d_in[9];
  float* out = (float*)d_out;

  char* p = (char*)d_ws;
  auto alloc = [&](size_t bytes) {
    char* r = p;
    p += (bytes + 255) & ~(size_t)255;
    return r;
  };
  unsigned short* Wg_all = (unsigned short*)alloc((size_t)9 * 1048576 * 2);  // [9][1024][1024]
  unsigned short* Wu_all = (unsigned short*)alloc((size_t)9 * 1048576 * 2);
  unsigned short* Wd_all = (unsigned short*)alloc((size_t)9 * 1048576 * 2);
  unsigned short* Xbf    = (unsigned short*)alloc((size_t)TTOK * 1024 * 2);  // bf16 hidden
  unsigned short* Hall   = (unsigned short*)alloc((size_t)MROWS * 1024 * 2);
  unsigned short* Yall   = (unsigned short*)alloc((size_t)MROWS * 1024 * 2);
  int*   cnt      = (int*)alloc(NE * 4);        // persistent; masked, never reset
  int*   rowsrc   = (int*)alloc((size_t)MROWS * 4);
  int*   inv      = (int*)alloc((size_t)TTOK * KTOP * 4);
  float* rowscale = (float*)alloc((size_t)MROWS * 4);

  // No memset: routing counters are used modulo CPER (see prep branch).

  prep_transw_kernel<<<dim3(16, 16, 28), 256, 0, stream>>>(
      w_gate, w_up, w_down, sw_gate, sw_up, sw_down, Wg_all, Wu_all, Wd_all,
      hidden, sgw, topk_i, topk_w, cnt, rowsrc, inv, rowscale, Xbf);

  gemm1_kernel<<<dim3(8, 96), 256, 0, stream>>>(Xbf, rowsrc, Wg_all, Wu_all, Hall);
  gemm2_kernel<<<dim3(4, 96), 256, 0, stream>>>(Hall, Wd_all, rowscale, Yall);
  combine_kernel<<<2048, 256, 0, stream>>>(Yall, inv, out);
}